// Round 1
// baseline (17142.926 us; speedup 1.0000x reference)
//
#include <hip/hip_runtime.h>
#include <cstdint>
#include <cstddef>

typedef unsigned short u16;
typedef __attribute__((ext_vector_type(8))) short short8;
typedef __attribute__((ext_vector_type(4))) float floatx4;

#define B_ 64
#define T_ 256
#define TD_ 255
#define V_ 8000
#define E_ 512
#define H_ 1024
#define G_ 4096
#define NBLK 128

__device__ __forceinline__ u16 f2bf(float f) {
    union { float f; unsigned int u; } v; v.f = f;
    unsigned int r = v.u + 0x7fffu + ((v.u >> 16) & 1u);
    return (u16)(r >> 16);
}
__device__ __forceinline__ float bf2f(u16 h) {
    union { unsigned int u; float f; } v; v.u = ((unsigned int)h) << 16;
    return v.f;
}
__device__ __forceinline__ float sigm(float x) { return 1.f / (1.f + __expf(-x)); }

// ---------------- prep: fp32 -> bf16 weight/embedding conversion + token tables ----
__global__ __launch_bounds__(256) void prep_kernel(
    const float* __restrict__ encWih, const float* __restrict__ encWhh,
    const float* __restrict__ decWih, const float* __restrict__ decWhh,
    const float* __restrict__ outW, const float* __restrict__ encEmb,
    const float* __restrict__ decEmb, const int* __restrict__ seqs,
    u16* dWihE, u16* dWhhE, u16* dWihD, u16* dWhhD, u16* dOutW,
    u16* dEmbE, u16* dEmbD, int* tokE, int* tokD)
{
    int idx = blockIdx.x * 256 + threadIdx.x;
    if (idx < 2097152) { dWihE[idx] = f2bf(encWih[idx]); return; }
    idx -= 2097152;
    if (idx < 4194304) { dWhhE[idx] = f2bf(encWhh[idx]); return; }
    idx -= 4194304;
    if (idx < 2097152) { dWihD[idx] = f2bf(decWih[idx]); return; }
    idx -= 2097152;
    if (idx < 4194304) { dWhhD[idx] = f2bf(decWhh[idx]); return; }
    idx -= 4194304;
    if (idx < 8192000) { dOutW[idx] = f2bf(outW[idx]); return; }
    idx -= 8192000;
    if (idx < 4096000) { dEmbE[idx] = f2bf(encEmb[idx]); return; }
    idx -= 4096000;
    if (idx < 4096000) { dEmbD[idx] = f2bf(decEmb[idx]); return; }
    idx -= 4096000;
    if (idx < 16384) { int t = idx >> 6, b = idx & 63; tokE[idx] = seqs[b * T_ + t]; return; }
    idx -= 16384;
    if (idx < 16320) { int t = idx >> 6, b = idx & 63; tokD[idx] = (t == 0) ? 1 : seqs[b * T_ + t]; return; }
}

// ---------------- pre-GEMM: X[t*64+b][4096] = emb[tok] @ Wih^T + bias (bf16 out) ----
__global__ __launch_bounds__(256) void pregemm_kernel(
    const u16* __restrict__ emb, const u16* __restrict__ wih,
    const float* __restrict__ bias, const int* __restrict__ tok,
    u16* __restrict__ X)
{
    const int tid = threadIdx.x;
    const int w = tid >> 6, lane = tid & 63, lo = lane & 15, q = lane >> 4;
    const int mb = blockIdx.x, nb = blockIdx.y;

    const int m_row = mb * 64 + w * 16 + lo;
    const u16* arow = emb + (size_t)tok[m_row] * E_ + q * 8;
    const u16* brow = wih + (size_t)(nb * 64 + lo) * E_ + q * 8;

    floatx4 acc[4];
#pragma unroll
    for (int nt = 0; nt < 4; ++nt) {
        float bv = bias[nb * 64 + nt * 16 + lo];
        acc[nt] = (floatx4){bv, bv, bv, bv};
    }
#pragma unroll 4
    for (int k0 = 0; k0 < E_; k0 += 32) {
        short8 a = *(const short8*)(arow + k0);
#pragma unroll
        for (int nt = 0; nt < 4; ++nt) {
            short8 b = *(const short8*)(brow + (size_t)nt * 16 * E_ + k0);
            acc[nt] = __builtin_amdgcn_mfma_f32_16x16x32_bf16(a, b, acc[nt], 0, 0, 0);
        }
    }
#pragma unroll
    for (int nt = 0; nt < 4; ++nt)
#pragma unroll
        for (int r = 0; r < 4; ++r) {
            int m = mb * 64 + w * 16 + q * 4 + r;
            int j = nb * 64 + nt * 16 + lo;
            X[(size_t)m * G_ + j] = f2bf(acc[nt][r]);
        }
}

// ---------------- persistent recurrent LSTM kernel ----------------
__device__ __forceinline__ void load_whh(const u16* __restrict__ whh, int u0, int tid,
                                         u16* whh_lds)
{
    // 32 rows (i,f,g,o x 8 units), 128 16B-chunks per row; XOR-swizzle chunks by (row&7)
    for (int idx = tid; idx < 32 * 128; idx += 256) {
        int jl = idx >> 7, ch = idx & 127;
        int grow = (jl >> 3) * H_ + u0 + (jl & 7);
        int4 v = *(const int4*)(whh + (size_t)grow * H_ + ch * 8);
        *(int4*)(whh_lds + jl * 1024 + ((ch ^ (jl & 7)) << 3)) = v;
    }
}

__device__ __forceinline__ void grid_barrier(unsigned int* flags, int bk, int tid,
                                             unsigned int target)
{
    __threadfence();        // release: h publishes visible at agent scope
    __syncthreads();
    if (tid == 0)
        __hip_atomic_store(&flags[bk * 16], target, __ATOMIC_RELEASE, __HIP_MEMORY_SCOPE_AGENT);
    if (tid < NBLK) {
        while (__hip_atomic_load(&flags[tid * 16], __ATOMIC_RELAXED, __HIP_MEMORY_SCOPE_AGENT) < target) {}
    }
    __syncthreads();
    __threadfence();        // acquire: subsequent h reads see fresh data
}

__device__ __forceinline__ void lstm_step(
    const u16* __restrict__ Xt, const u16* __restrict__ hsrc, u16* __restrict__ hdst,
    const u16* whh_lds, float* cst, int tid, int u0)
{
    const int w = tid >> 6, lane = tid & 63, lo = lane & 15, q = lane >> 4;

    floatx4 acc0, acc1;
    {
        const int jg0 = ((lo >> 3) * H_) + u0 + (lo & 7);          // tile0: i/f rows
        const int jg1 = (((16 + lo) >> 3) * H_) + u0 + (lo & 7);   // tile1: g/o rows
#pragma unroll
        for (int r = 0; r < 4; ++r) {
            int m = w * 16 + q * 4 + r;
            acc0[r] = bf2f(Xt[(size_t)m * G_ + jg0]);
            acc1[r] = bf2f(Xt[(size_t)m * G_ + jg1]);
        }
    }
    const u16* arow = hsrc + (size_t)(w * 16 + lo) * H_ + q * 8;
    const u16* ldsrow0 = whh_lds + lo * 1024;
    const u16* ldsrow1 = whh_lds + (16 + lo) * 1024;
    const int sw = lo & 7;
#pragma unroll 4
    for (int k0 = 0; k0 < H_; k0 += 32) {
        int cidx = (k0 >> 3) + q;
        int coff = ((cidx ^ sw) << 3);
        short8 a = *(const short8*)(arow + k0);
        short8 b0 = *(const short8*)(ldsrow0 + coff);
        short8 b1 = *(const short8*)(ldsrow1 + coff);
        acc0 = __builtin_amdgcn_mfma_f32_16x16x32_bf16(a, b0, acc0, 0, 0, 0);
        acc1 = __builtin_amdgcn_mfma_f32_16x16x32_bf16(a, b1, acc1, 0, 0, 0);
    }
    // gate combine: tile0 = i (lo<8) / f (lo>=8); tile1 = g / o
#pragma unroll
    for (int r = 0; r < 4; ++r) {
        float x0 = acc0[r], x1 = acc1[r];
        float y0 = __shfl_xor(x0, 8, 64);
        float y1 = __shfl_xor(x1, 8, 64);
        if (lo < 8) {
            float cn = sigm(y0) * cst[r] + sigm(x0) * tanhf(x1);
            cst[r] = cn;
            float h = sigm(y1) * tanhf(cn);
            hdst[(size_t)(w * 16 + q * 4 + r) * H_ + u0 + lo] = f2bf(h);
        }
    }
}

__global__ __launch_bounds__(256) void lstm_kernel(
    const u16* __restrict__ Xenc, const u16* __restrict__ Xdec,
    const u16* __restrict__ whhE, const u16* __restrict__ whhD,
    u16* __restrict__ hbuf, const u16* __restrict__ hinit,
    u16* __restrict__ Hdec, unsigned int* flags)
{
    __shared__ __align__(16) u16 whh_lds[32 * 1024];   // exactly 64 KB
    const int tid = threadIdx.x;
    const int bk = blockIdx.x;
    const int u0 = bk * 8;
    float cst[4] = {0.f, 0.f, 0.f, 0.f};

    load_whh(whhE, u0, tid, whh_lds);
    __syncthreads();

    unsigned int gstep = 0;
#pragma unroll 1
    for (int t = 0; t < T_; ++t) {
        const u16* hsrc = (t == 0) ? hinit : (hbuf + ((t - 1) & 1) * (B_ * H_));
        u16* hdst = hbuf + (t & 1) * (B_ * H_);
        lstm_step(Xenc + (size_t)t * B_ * G_, hsrc, hdst, whh_lds, cst, tid, u0);
        ++gstep;
        grid_barrier(flags, bk, tid, gstep);
    }

    load_whh(whhD, u0, tid, whh_lds);
    __syncthreads();

#pragma unroll 1
    for (int t = 0; t < TD_; ++t) {
        const u16* hsrc = (t == 0) ? (hbuf + B_ * H_) : (Hdec + (size_t)(t - 1) * B_ * H_);
        u16* hdst = Hdec + (size_t)t * B_ * H_;
        lstm_step(Xdec + (size_t)t * B_ * G_, hsrc, hdst, whh_lds, cst, tid, u0);
        if (t != TD_ - 1) { ++gstep; grid_barrier(flags, bk, tid, gstep); }
    }
}

// ---------------- logits GEMM: out[b][t][v] = Hdec[t*64+b] . outW[v] + out_b[v] ----
__global__ __launch_bounds__(256) void logits_kernel(
    const u16* __restrict__ Hdec, const u16* __restrict__ outW,
    const float* __restrict__ outB, float* __restrict__ out)
{
    const int tid = threadIdx.x;
    const int w = tid >> 6, lane = tid & 63, lo = lane & 15, q = lane >> 4;
    const int mb = blockIdx.x, nb = blockIdx.y;

    const u16* arow = Hdec + (size_t)(mb * 64 + w * 16 + lo) * H_ + q * 8;
    const u16* brow = outW + (size_t)(nb * 64 + lo) * H_ + q * 8;

    floatx4 acc[4];
#pragma unroll
    for (int nt = 0; nt < 4; ++nt) {
        float bv = outB[nb * 64 + nt * 16 + lo];
        acc[nt] = (floatx4){bv, bv, bv, bv};
    }
#pragma unroll 4
    for (int k0 = 0; k0 < H_; k0 += 32) {
        short8 a = *(const short8*)(arow + k0);
#pragma unroll
        for (int nt = 0; nt < 4; ++nt) {
            short8 b = *(const short8*)(brow + (size_t)nt * 16 * H_ + k0);
            acc[nt] = __builtin_amdgcn_mfma_f32_16x16x32_bf16(a, b, acc[nt], 0, 0, 0);
        }
    }
#pragma unroll
    for (int nt = 0; nt < 4; ++nt)
#pragma unroll
        for (int r = 0; r < 4; ++r) {
            int m = mb * 64 + w * 16 + q * 4 + r;
            int t = m >> 6, b = m & 63;
            int v = nb * 64 + nt * 16 + lo;
            out[((size_t)b * TD_ + t) * V_ + v] = acc[nt][r];
        }
}

// ---------------- launch ----------------
extern "C" void kernel_launch(void* const* d_in, const int* in_sizes, int n_in,
                              void* d_out, int out_size, void* d_ws, size_t ws_size,
                              hipStream_t stream) {
    const int*   seqs   = (const int*)d_in[1];
    const float* encEmb = (const float*)d_in[2];
    const float* encWih = (const float*)d_in[3];
    const float* encWhh = (const float*)d_in[4];
    const float* encB   = (const float*)d_in[5];
    const float* decEmb = (const float*)d_in[6];
    const float* decWih = (const float*)d_in[7];
    const float* decWhh = (const float*)d_in[8];
    const float* decB   = (const float*)d_in[9];
    const float* outW   = (const float*)d_in[10];
    const float* outB   = (const float*)d_in[11];
    float* out = (float*)d_out;

    char* base = (char*)d_ws;
    size_t off = 0;
    auto carve = [&](size_t bytes) -> void* {
        void* r = base + off;
        off += (bytes + 255) & ~(size_t)255;
        return r;
    };
    u16* dWihE = (u16*)carve((size_t)G_ * E_ * 2);
    u16* dWhhE = (u16*)carve((size_t)G_ * H_ * 2);
    u16* dWihD = (u16*)carve((size_t)G_ * E_ * 2);
    u16* dWhhD = (u16*)carve((size_t)G_ * H_ * 2);
    u16* dOutW = (u16*)carve((size_t)V_ * H_ * 2);
    u16* dEmbE = (u16*)carve((size_t)V_ * E_ * 2);
    u16* dEmbD = (u16*)carve((size_t)V_ * E_ * 2);
    int* tokE  = (int*)carve((size_t)T_ * B_ * 4);
    int* tokD  = (int*)carve((size_t)TD_ * B_ * 4);
    unsigned int* flags = (unsigned int*)carve(NBLK * 16 * 4);   // 8192 B
    u16* hinit = (u16*)carve((size_t)B_ * H_ * 2);               // 131072 B (zeros)
    u16* hbuf  = (u16*)carve((size_t)2 * B_ * H_ * 2);
    u16* Xenc  = (u16*)carve((size_t)T_ * B_ * G_ * 2);
    u16* Xdec  = (u16*)carve((size_t)TD_ * B_ * G_ * 2);
    u16* Hdec  = (u16*)carve((size_t)TD_ * B_ * H_ * 2);

    // zero flags + hinit (they are contiguous carves)
    hipMemsetAsync(flags, 0, NBLK * 16 * 4 + (size_t)B_ * H_ * 2, stream);

    const int PREP_TOTAL = 2097152 + 4194304 + 2097152 + 4194304 + 8192000
                         + 4096000 + 4096000 + 16384 + 16320;
    prep_kernel<<<(PREP_TOTAL + 255) / 256, 256, 0, stream>>>(
        encWih, encWhh, decWih, decWhh, outW, encEmb, decEmb, seqs,
        dWihE, dWhhE, dWihD, dWhhD, dOutW, dEmbE, dEmbD, tokE, tokD);

    pregemm_kernel<<<dim3(T_, G_ / 64), 256, 0, stream>>>(dEmbE, dWihE, encB, tokE, Xenc);
    pregemm_kernel<<<dim3(TD_, G_ / 64), 256, 0, stream>>>(dEmbD, dWihD, decB, tokD, Xdec);

    lstm_kernel<<<dim3(NBLK), dim3(256), 0, stream>>>(
        Xenc, Xdec, dWhhE, dWhhD, hbuf, hinit, Hdec, flags);

    logits_kernel<<<dim3(TD_, V_ / 64), 256, 0, stream>>>(Hdec, dOutW, outB, out);
}

// Round 2
// 9508.350 us; speedup vs baseline: 1.8029x; 1.8029x over previous
//
#include <hip/hip_runtime.h>
#include <cstdint>
#include <cstddef>

typedef unsigned short u16;
typedef unsigned long long u64;
typedef __attribute__((ext_vector_type(8))) short short8;
typedef __attribute__((ext_vector_type(4))) float floatx4;

#define B_ 64
#define T_ 256
#define TD_ 255
#define V_ 8000
#define E_ 512
#define H_ 1024
#define G_ 4096
#define NBLK 128

__device__ __forceinline__ u16 f2bf(float f) {
    union { float f; unsigned int u; } v; v.f = f;
    unsigned int r = v.u + 0x7fffu + ((v.u >> 16) & 1u);
    return (u16)(r >> 16);
}
__device__ __forceinline__ float bf2f(u16 h) {
    union { unsigned int u; float f; } v; v.u = ((unsigned int)h) << 16;
    return v.f;
}
__device__ __forceinline__ float sigm(float x) { return 1.f / (1.f + __expf(-x)); }

// ---------------- prep: fp32 -> bf16 weight/embedding conversion + token tables ----
__global__ __launch_bounds__(256) void prep_kernel(
    const float* __restrict__ encWih, const float* __restrict__ encWhh,
    const float* __restrict__ decWih, const float* __restrict__ decWhh,
    const float* __restrict__ outW, const float* __restrict__ encEmb,
    const float* __restrict__ decEmb, const int* __restrict__ seqs,
    u16* dWihE, u16* dWhhE, u16* dWihD, u16* dWhhD, u16* dOutW,
    u16* dEmbE, u16* dEmbD, int* tokE, int* tokD)
{
    int idx = blockIdx.x * 256 + threadIdx.x;
    if (idx < 2097152) { dWihE[idx] = f2bf(encWih[idx]); return; }
    idx -= 2097152;
    if (idx < 4194304) { dWhhE[idx] = f2bf(encWhh[idx]); return; }
    idx -= 4194304;
    if (idx < 2097152) { dWihD[idx] = f2bf(decWih[idx]); return; }
    idx -= 2097152;
    if (idx < 4194304) { dWhhD[idx] = f2bf(decWhh[idx]); return; }
    idx -= 4194304;
    if (idx < 8192000) { dOutW[idx] = f2bf(outW[idx]); return; }
    idx -= 8192000;
    if (idx < 4096000) { dEmbE[idx] = f2bf(encEmb[idx]); return; }
    idx -= 4096000;
    if (idx < 4096000) { dEmbD[idx] = f2bf(decEmb[idx]); return; }
    idx -= 4096000;
    if (idx < 16384) { int t = idx >> 6, b = idx & 63; tokE[idx] = seqs[b * T_ + t]; return; }
    idx -= 16384;
    if (idx < 16320) { int t = idx >> 6, b = idx & 63; tokD[idx] = (t == 0) ? 1 : seqs[b * T_ + t]; return; }
}

// ---------------- pre-GEMM: X slices per (t, lstm-block), bf16 out ----
// Xp[((t*128 + bk)*32 + jl)*64 + m], jl = gate*8 + (col&7), m = batch row 0..63
__global__ __launch_bounds__(256) void pregemm_kernel(
    const u16* __restrict__ emb, const u16* __restrict__ wih,
    const float* __restrict__ bias, const int* __restrict__ tok,
    u16* __restrict__ X)
{
    const int tid = threadIdx.x;
    const int w = tid >> 6, lane = tid & 63, lo = lane & 15, q = lane >> 4;
    const int mb = blockIdx.x, nb = blockIdx.y;

    const int m_row = mb * 64 + w * 16 + lo;
    const u16* arow = emb + (size_t)tok[m_row] * E_ + q * 8;
    const u16* brow = wih + (size_t)(nb * 64 + lo) * E_ + q * 8;

    floatx4 acc[4];
#pragma unroll
    for (int nt = 0; nt < 4; ++nt) {
        float bv = bias[nb * 64 + nt * 16 + lo];
        acc[nt] = (floatx4){bv, bv, bv, bv};
    }
#pragma unroll 4
    for (int k0 = 0; k0 < E_; k0 += 32) {
        short8 a = *(const short8*)(arow + k0);
#pragma unroll
        for (int nt = 0; nt < 4; ++nt) {
            short8 b = *(const short8*)(brow + (size_t)nt * 16 * E_ + k0);
            acc[nt] = __builtin_amdgcn_mfma_f32_16x16x32_bf16(a, b, acc[nt], 0, 0, 0);
        }
    }
#pragma unroll
    for (int nt = 0; nt < 4; ++nt)
#pragma unroll
        for (int r = 0; r < 4; ++r) {
            int m = w * 16 + q * 4 + r;                 // local batch row
            int j = nb * 64 + nt * 16 + lo;             // global gate-col 0..4095
            int g = j >> 10, hc = j & 1023;
            int bk2 = hc >> 3, cb = hc & 7;
            X[(((size_t)mb * NBLK + bk2) * 32 + (g * 8 + cb)) * 64 + m] = f2bf(acc[nt][r]);
        }
}

// ---------------- persistent recurrent LSTM kernel ----------------
__device__ __forceinline__ void load_whh(const u16* __restrict__ whh, int u0, int tid,
                                         u16* whh_lds)
{
    // 32 rows (i,f,g,o x 8 units), 128 16B-chunks per row; XOR-swizzle chunks by (row&7)
    for (int idx = tid; idx < 32 * 128; idx += 256) {
        int jl = idx >> 7, ch = idx & 127;
        int grow = (jl >> 3) * H_ + u0 + (jl & 7);
        int4 v = *(const int4*)(whh + (size_t)grow * H_ + ch * 8);
        *(int4*)(whh_lds + jl * 1024 + ((ch ^ (jl & 7)) << 3)) = v;
    }
}

// Fence-free grid barrier: h was published via sc1 (agent-scope relaxed) stores.
// s_waitcnt vmcnt(0) guarantees they reached the coherent point (LLC) before the
// flag store issues. No __threadfence -> no L2 writeback/invalidate per step.
__device__ __forceinline__ void grid_barrier(unsigned int* flags, int bk, int tid,
                                             unsigned int target)
{
    asm volatile("s_waitcnt vmcnt(0)" ::: "memory");
    __syncthreads();
    if (tid == 0)
        __hip_atomic_store(&flags[bk * 32], target, __ATOMIC_RELAXED, __HIP_MEMORY_SCOPE_AGENT);
    if (tid < NBLK) {
        while (__hip_atomic_load(&flags[tid * 32], __ATOMIC_RELAXED, __HIP_MEMORY_SCOPE_AGENT) < target) {}
    }
    __syncthreads();
}

__device__ __forceinline__ void lstm_step(
    const u16* __restrict__ Xs,      // this (t,bk)'s contiguous 2048-elem slice
    const u16* __restrict__ hsrc, u16* __restrict__ hdst,
    const u16* whh_lds, float* cst, int tid, int u0)
{
    const int w = tid >> 6, lane = tid & 63, lo = lane & 15, q = lane >> 4;

    // Issue ALL h loads up front (agent-scope relaxed = global_load sc1, fresh from LLC)
    const u16* arow = hsrc + (size_t)(w * 16 + lo) * H_ + q * 8;
    u64 areg[64];
#pragma unroll
    for (int k = 0; k < 32; ++k) {
        const u64* p = (const u64*)(arow + k * 32);
        areg[2 * k]     = __hip_atomic_load(p,     __ATOMIC_RELAXED, __HIP_MEMORY_SCOPE_AGENT);
        areg[2 * k + 1] = __hip_atomic_load(p + 1, __ATOMIC_RELAXED, __HIP_MEMORY_SCOPE_AGENT);
    }

    floatx4 acc0, acc1;
#pragma unroll
    for (int r = 0; r < 4; ++r) {
        int m = w * 16 + q * 4 + r;
        acc0[r] = bf2f(Xs[lo * 64 + m]);          // jl0 = lo        (gates i/f)
        acc1[r] = bf2f(Xs[(16 + lo) * 64 + m]);   // jl1 = 16 + lo   (gates g/o)
    }
    const u16* ldsrow0 = whh_lds + lo * 1024;
    const u16* ldsrow1 = whh_lds + (16 + lo) * 1024;
    const int sw = lo & 7;
#pragma unroll
    for (int i = 0; i < 32; ++i) {
        int cidx = (i << 2) + q;
        int coff = ((cidx ^ sw) << 3);
        union { u64 u[2]; short8 s; } av;
        av.u[0] = areg[2 * i]; av.u[1] = areg[2 * i + 1];
        short8 b0 = *(const short8*)(ldsrow0 + coff);
        short8 b1 = *(const short8*)(ldsrow1 + coff);
        acc0 = __builtin_amdgcn_mfma_f32_16x16x32_bf16(av.s, b0, acc0, 0, 0, 0);
        acc1 = __builtin_amdgcn_mfma_f32_16x16x32_bf16(av.s, b1, acc1, 0, 0, 0);
    }
    // gate combine: tile0 = i (lo<8) / f (lo>=8); tile1 = g / o
#pragma unroll
    for (int r = 0; r < 4; ++r) {
        float x0 = acc0[r], x1 = acc1[r];
        float y0 = __shfl_xor(x0, 8, 64);
        float y1 = __shfl_xor(x1, 8, 64);
        float cn = sigm(y0) * cst[r] + sigm(x0) * tanhf(x1);
        cst[r] = cn;
        float h = sigm(y1) * tanhf(cn);
        unsigned int bits = (unsigned int)f2bf(h);
        unsigned int pb = (unsigned int)__shfl_xor((int)bits, 1, 64);
        if (lo < 8 && (lo & 1) == 0) {
            int row = w * 16 + q * 4 + r;
            unsigned int val = bits | (pb << 16);
            __hip_atomic_store((unsigned int*)(hdst + (size_t)row * H_ + u0 + lo), val,
                               __ATOMIC_RELAXED, __HIP_MEMORY_SCOPE_AGENT);
        }
    }
}

__global__ __launch_bounds__(256, 1) void lstm_kernel(
    const u16* __restrict__ Xenc, const u16* __restrict__ Xdec,
    const u16* __restrict__ whhE, const u16* __restrict__ whhD,
    u16* __restrict__ hbuf, const u16* __restrict__ hinit,
    u16* __restrict__ Hdec, unsigned int* flags)
{
    __shared__ __align__(16) u16 whh_lds[32 * 1024];   // exactly 64 KB
    const int tid = threadIdx.x;
    const int bk = blockIdx.x;
    const int u0 = bk * 8;
    float cst[4] = {0.f, 0.f, 0.f, 0.f};

    load_whh(whhE, u0, tid, whh_lds);
    __syncthreads();

    unsigned int gstep = 0;
#pragma unroll 1
    for (int t = 0; t < T_; ++t) {
        const u16* hsrc = (t == 0) ? hinit : (hbuf + ((t - 1) & 1) * (B_ * H_));
        u16* hdst = hbuf + (t & 1) * (B_ * H_);
        lstm_step(Xenc + ((size_t)t * NBLK + bk) * 2048, hsrc, hdst, whh_lds, cst, tid, u0);
        ++gstep;
        grid_barrier(flags, bk, tid, gstep);
    }

    load_whh(whhD, u0, tid, whh_lds);
    __syncthreads();

#pragma unroll 1
    for (int t = 0; t < TD_; ++t) {
        const u16* hsrc = (t == 0) ? (hbuf + B_ * H_) : (Hdec + (size_t)(t - 1) * B_ * H_);
        u16* hdst = Hdec + (size_t)t * B_ * H_;
        lstm_step(Xdec + ((size_t)t * NBLK + bk) * 2048, hsrc, hdst, whh_lds, cst, tid, u0);
        if (t != TD_ - 1) { ++gstep; grid_barrier(flags, bk, tid, gstep); }
    }
}

// ---------------- logits GEMM: out[b][t][v] = Hdec[t*64+b] . outW[v] + out_b[v] ----
__global__ __launch_bounds__(256) void logits_kernel(
    const u16* __restrict__ Hdec, const u16* __restrict__ outW,
    const float* __restrict__ outB, float* __restrict__ out)
{
    const int tid = threadIdx.x;
    const int w = tid >> 6, lane = tid & 63, lo = lane & 15, q = lane >> 4;
    const int mb = blockIdx.x, nb = blockIdx.y;

    const u16* arow = Hdec + (size_t)(mb * 64 + w * 16 + lo) * H_ + q * 8;
    const u16* brow = outW + (size_t)(nb * 64 + lo) * H_ + q * 8;

    floatx4 acc[4];
#pragma unroll
    for (int nt = 0; nt < 4; ++nt) {
        float bv = outB[nb * 64 + nt * 16 + lo];
        acc[nt] = (floatx4){bv, bv, bv, bv};
    }
#pragma unroll 4
    for (int k0 = 0; k0 < H_; k0 += 32) {
        short8 a = *(const short8*)(arow + k0);
#pragma unroll
        for (int nt = 0; nt < 4; ++nt) {
            short8 b = *(const short8*)(brow + (size_t)nt * 16 * H_ + k0);
            acc[nt] = __builtin_amdgcn_mfma_f32_16x16x32_bf16(a, b, acc[nt], 0, 0, 0);
        }
    }
#pragma unroll
    for (int nt = 0; nt < 4; ++nt)
#pragma unroll
        for (int r = 0; r < 4; ++r) {
            int m = mb * 64 + w * 16 + q * 4 + r;
            int t = m >> 6, b = m & 63;
            int v = nb * 64 + nt * 16 + lo;
            out[((size_t)b * TD_ + t) * V_ + v] = acc[nt][r];
        }
}

// ---------------- launch ----------------
extern "C" void kernel_launch(void* const* d_in, const int* in_sizes, int n_in,
                              void* d_out, int out_size, void* d_ws, size_t ws_size,
                              hipStream_t stream) {
    const int*   seqs   = (const int*)d_in[1];
    const float* encEmb = (const float*)d_in[2];
    const float* encWih = (const float*)d_in[3];
    const float* encWhh = (const float*)d_in[4];
    const float* encB   = (const float*)d_in[5];
    const float* decEmb = (const float*)d_in[6];
    const float* decWih = (const float*)d_in[7];
    const float* decWhh = (const float*)d_in[8];
    const float* decB   = (const float*)d_in[9];
    const float* outW   = (const float*)d_in[10];
    const float* outB   = (const float*)d_in[11];
    float* out = (float*)d_out;

    char* base = (char*)d_ws;
    size_t off = 0;
    auto carve = [&](size_t bytes) -> void* {
        void* r = base + off;
        off += (bytes + 255) & ~(size_t)255;
        return r;
    };
    u16* dWihE = (u16*)carve((size_t)G_ * E_ * 2);
    u16* dWhhE = (u16*)carve((size_t)G_ * H_ * 2);
    u16* dWihD = (u16*)carve((size_t)G_ * E_ * 2);
    u16* dWhhD = (u16*)carve((size_t)G_ * H_ * 2);
    u16* dOutW = (u16*)carve((size_t)V_ * H_ * 2);
    u16* dEmbE = (u16*)carve((size_t)V_ * E_ * 2);
    u16* dEmbD = (u16*)carve((size_t)V_ * E_ * 2);
    int* tokE  = (int*)carve((size_t)T_ * B_ * 4);
    int* tokD  = (int*)carve((size_t)TD_ * B_ * 4);
    unsigned int* flags = (unsigned int*)carve(NBLK * 32 * 4);   // 16384 B, 128B-padded flags
    u16* hinit = (u16*)carve((size_t)B_ * H_ * 2);               // 131072 B (zeros)
    u16* hbuf  = (u16*)carve((size_t)2 * B_ * H_ * 2);
    u16* Xenc  = (u16*)carve((size_t)T_ * B_ * G_ * 2);
    u16* Xdec  = (u16*)carve((size_t)TD_ * B_ * G_ * 2);
    u16* Hdec  = (u16*)carve((size_t)TD_ * B_ * H_ * 2);

    // zero flags + hinit (they are contiguous carves; 16384 is 256-aligned)
    hipMemsetAsync(flags, 0, NBLK * 32 * 4 + (size_t)B_ * H_ * 2, stream);

    const int PREP_TOTAL = 2097152 + 4194304 + 2097152 + 4194304 + 8192000
                         + 4096000 + 4096000 + 16384 + 16320;
    prep_kernel<<<(PREP_TOTAL + 255) / 256, 256, 0, stream>>>(
        encWih, encWhh, decWih, decWhh, outW, encEmb, decEmb, seqs,
        dWihE, dWhhE, dWihD, dWhhD, dOutW, dEmbE, dEmbD, tokE, tokD);

    pregemm_kernel<<<dim3(T_, G_ / 64), 256, 0, stream>>>(dEmbE, dWihE, encB, tokE, Xenc);
    pregemm_kernel<<<dim3(TD_, G_ / 64), 256, 0, stream>>>(dEmbD, dWihD, decB, tokD, Xdec);

    lstm_kernel<<<dim3(NBLK), dim3(256), 0, stream>>>(
        Xenc, Xdec, dWhhE, dWhhD, hbuf, hinit, Hdec, flags);

    logits_kernel<<<dim3(TD_, V_ / 64), 256, 0, stream>>>(Hdec, dOutW, outB, out);
}